// Round 9
// baseline (268.604 us; speedup 1.0000x reference)
//
#include <hip/hip_runtime.h>

// Problem constants (fixed by the reference)
#define BATCH 256
#define CDIM  2048
#define HW    49
#define KDIM  16

#define NCHUNK  8                // c-chunks per image
#define CC      256              // c per chunk
#define CHUNK_B (CC * HW * 4)    // 50176 bytes == 49 * 1024
#define CHUNK_F (CC * HW)        // 12544 floats

// async global->LDS DMA, 16 B per lane: LDS dst = wave-uniform base + lane*16
// (linear); global src per-lane. Both 16B-aligned here.
#define GLDS(g, l) __builtin_amdgcn_global_load_lds(                        \
        (const __attribute__((address_space(1))) unsigned int*)(g),          \
        (__attribute__((address_space(3))) unsigned int*)(l), 16, 0, 0)
#define WAITVM(N) do { asm volatile("s_waitcnt vmcnt(" #N ")" ::: "memory"); \
                       __builtin_amdgcn_sched_barrier(0); } while (0)
#define SBAR()    __builtin_amdgcn_s_barrier()

// Workspace (floats): wT[2048*16] at 0; pscr[256*784] at 32768.
//   conv writes P_bn[b][hw][k] directly (one block per image -> no atomics).

// ---------------------------------------------------------------------------
// prep: wT[c][k] = w16[k][c] * gamma[k]*rsqrt(var+eps)/49  (BN scale + pool folded)
// ---------------------------------------------------------------------------
__global__ __launch_bounds__(256) void prep_kernel(
    const float* __restrict__ w16,
    const float* __restrict__ gamma, const float* __restrict__ var,
    float* __restrict__ wT)
{
    const int idx = blockIdx.x * 256 + threadIdx.x;   // grid 128 -> 32768 threads
    const int c = idx >> 4, k = idx & 15;
    const float inv = gamma[k] * rsqrtf(var[k] + 1e-5f) * (1.0f / 49.0f);
    wT[idx] = w16[k * CDIM + c] * inv;
}

// ---------------------------------------------------------------------------
// conv: P_bn[b][hw][k] = shift[k]/49 + sum_c wT[c][k]*fm[c][hw]
// grid = BATCH (1 block/image/CU), block = 512 (8 waves).
// Double-buffered GLDS pipeline over 8 chunks of 256 c (50 KB each):
//   issue chunk t+1 (waves 0..6, 7 loads each) -> vmcnt(7) -> s_barrier ->
//   compute chunk t -> s_barrier.  Loads never drain to 0 in the loop (T3/T4).
// w via wave-uniform s_load; lane = hw; wave owns 32 c per chunk.
// ---------------------------------------------------------------------------
__global__ __launch_bounds__(512) void conv_kernel(
    const float* __restrict__ fm, const float* __restrict__ wT,
    const float* __restrict__ gamma, const float* __restrict__ beta,
    const float* __restrict__ mean,  const float* __restrict__ var,
    float* __restrict__ pscr)
{
    __shared__ __align__(16) float buf0[CHUNK_F];     // 50176 B
    __shared__ __align__(16) float buf1[CHUNK_F];     // 50176 B
    __shared__ __align__(16) float red[8 * KDIM * 52]; // 26624 B  (total ~124 KB)

    const int tid  = threadIdx.x;
    const int b    = blockIdx.x;
    const int wavu = __builtin_amdgcn_readfirstlane(tid >> 6);
    const int lane = tid & 63;
    const int hwi  = lane < HW ? lane : HW - 1;       // clamp; lanes>=49 discarded

    const char* gb = (const char*)fm + (size_t)b * (CDIM * HW * 4);

    // prologue: issue chunk 0 (waves 0..6, 7 x 1024B each; wave 7 idle)
    if (wavu < 7) {
        #pragma unroll
        for (int i = 0; i < 7; ++i) {
            const int j = wavu * 7 + i;               // 0..48
            GLDS(gb + j * 1024 + lane * 16, (char*)buf0 + j * 1024);
        }
    }

    float acc[KDIM];
    #pragma unroll
    for (int k = 0; k < KDIM; ++k) acc[k] = 0.f;

    for (int t = 0; t < NCHUNK; ++t) {
        float* cur = (t & 1) ? buf1 : buf0;
        float* nxt = (t & 1) ? buf0 : buf1;

        if (t < NCHUNK - 1) {
            if (wavu < 7) {
                #pragma unroll
                for (int i = 0; i < 7; ++i) {
                    const int j = wavu * 7 + i;
                    GLDS(gb + (size_t)(t + 1) * CHUNK_B + j * 1024 + lane * 16,
                         (char*)nxt + j * 1024);
                }
            }
            WAITVM(7);       // chunk t landed; chunk t+1's 7 stay in flight
        } else {
            WAITVM(0);       // epilogue drain
        }
        SBAR();              // all waves past their own wait -> chunk t visible

        // compute chunk t: this wave's 32 c's
        const float4* __restrict__ wq =
            (const float4*)(wT + (size_t)((t * CC + wavu * 32) << 4));
        #pragma unroll 8
        for (int cc = 0; cc < 32; ++cc) {
            const float fv = cur[(wavu * 32 + cc) * HW + hwi];  // ds_read_b32, 2-way
            const float4 w0 = wq[cc * 4 + 0];                   // uniform -> s_load
            const float4 w1 = wq[cc * 4 + 1];
            const float4 w2 = wq[cc * 4 + 2];
            const float4 w3 = wq[cc * 4 + 3];
            acc[0]  += w0.x * fv; acc[1]  += w0.y * fv; acc[2]  += w0.z * fv; acc[3]  += w0.w * fv;
            acc[4]  += w1.x * fv; acc[5]  += w1.y * fv; acc[6]  += w1.z * fv; acc[7]  += w1.w * fv;
            acc[8]  += w2.x * fv; acc[9]  += w2.y * fv; acc[10] += w2.z * fv; acc[11] += w2.w * fv;
            acc[12] += w3.x * fv; acc[13] += w3.y * fv; acc[14] += w3.z * fv; acc[15] += w3.w * fv;
        }
        SBAR();              // reads of cur done -> safe to refill next iteration
    }

    // reduce 8 wave-partials + BN shift -> P_bn[b][hw][k]
    if (lane < HW) {
        #pragma unroll
        for (int k = 0; k < KDIM; ++k)
            red[wavu * (KDIM * 52) + k * 52 + lane] = acc[k];
    }
    __syncthreads();
    for (int p = tid; p < HW * KDIM; p += 512) {      // p = hw*16 + k
        const int k = p & 15, hw = p >> 4;
        const int a = k * 52 + hw;
        float s = 0.f;
        #pragma unroll
        for (int w = 0; w < 8; ++w) s += red[w * 832 + a];
        const float inv = gamma[k] * rsqrtf(var[k] + 1e-5f);
        pscr[(size_t)b * 784 + p] = s + (beta[k] - mean[k] * inv) * (1.0f / 49.0f);
    }
}

// ---------------------------------------------------------------------------
// bp: out[b][k][c] = sum_hw P_bn[hw][k] * fm[c][hw]
// grid = BATCH (1 block/image/CU), block = 512.
// Producer/consumer split (T14): waves 4..7 DMA (13 x 1024B each, 3 pad slots),
// waves 0..3 compute (1 c per thread per chunk; P via uniform s_load).
// Same double-buffer + counted-vmcnt schedule as conv.
// ---------------------------------------------------------------------------
__global__ __launch_bounds__(512) void bp_kernel(
    const float* __restrict__ fm, const float* __restrict__ pscr,
    float* __restrict__ out)
{
    __shared__ __align__(16) float buf0[CHUNK_F];     // 50176 B
    __shared__ __align__(16) float buf1[CHUNK_F];     // 50176 B
    __shared__ __align__(16) float pad[3 * 256];      // 3 KB dummy (never read)

    const int tid  = threadIdx.x;
    const int b    = blockIdx.x;
    const int wavu = __builtin_amdgcn_readfirstlane(tid >> 6);
    const int lane = tid & 63;
    const bool dma = (wavu >= 4);
    const int  w4  = wavu - 4;

    const char* gb = (const char*)fm + (size_t)b * (CDIM * HW * 4);

#define BP_ISSUE(T, DSTBUF) do {                                             \
        _Pragma("unroll")                                                    \
        for (int i = 0; i < 13; ++i) {                                       \
            const int j  = w4 * 13 + i;               /* 0..51 */            \
            const int jj = j < 49 ? j : 48;                                  \
            char* dst = (j < 49) ? (char*)(DSTBUF) + j * 1024                \
                                 : (char*)pad + (j - 49) * 1024;             \
            GLDS(gb + (size_t)(T) * CHUNK_B + jj * 1024 + lane * 16, dst);   \
        } } while (0)

    if (dma) BP_ISSUE(0, buf0);

    const float4* __restrict__ P4 = (const float4*)(pscr + (size_t)b * 784);

    for (int t = 0; t < NCHUNK; ++t) {
        float* cur = (t & 1) ? buf1 : buf0;
        float* nxt = (t & 1) ? buf0 : buf1;

        if (dma) {
            if (t < NCHUNK - 1) { BP_ISSUE(t + 1, nxt); WAITVM(13); }
            else                { WAITVM(0); }
        }
        SBAR();              // chunk t fully in LDS for everyone

        if (!dma) {          // waves 0..3: thread owns c = t*256 + tid
            float a[KDIM];
            #pragma unroll
            for (int k = 0; k < KDIM; ++k) a[k] = 0.f;
            const float* row = cur + tid * HW;        // stride 49 -> 2-way, free
            #pragma unroll
            for (int hw = 0; hw < HW; ++hw) {
                const float fv = row[hw];
                const float4 p0 = P4[hw * 4 + 0];     // uniform -> s_load
                const float4 p1 = P4[hw * 4 + 1];
                const float4 p2 = P4[hw * 4 + 2];
                const float4 p3 = P4[hw * 4 + 3];
                a[0]  += p0.x * fv; a[1]  += p0.y * fv; a[2]  += p0.z * fv; a[3]  += p0.w * fv;
                a[4]  += p1.x * fv; a[5]  += p1.y * fv; a[6]  += p1.z * fv; a[7]  += p1.w * fv;
                a[8]  += p2.x * fv; a[9]  += p2.y * fv; a[10] += p2.z * fv; a[11] += p2.w * fv;
                a[12] += p3.x * fv; a[13] += p3.y * fv; a[14] += p3.z * fv; a[15] += p3.w * fv;
            }
            float* ob = out + (size_t)b * (KDIM * CDIM) + t * CC + tid;
            #pragma unroll
            for (int k = 0; k < KDIM; ++k) ob[k * CDIM] = a[k];
        }
        SBAR();              // reads of cur done -> safe to refill
    }
#undef BP_ISSUE
}

extern "C" void kernel_launch(void* const* d_in, const int* in_sizes, int n_in,
                              void* d_out, int out_size, void* d_ws, size_t ws_size,
                              hipStream_t stream) {
    const float* fm    = (const float*)d_in[0];
    const float* w16   = (const float*)d_in[1];
    const float* gamma = (const float*)d_in[2];
    const float* beta  = (const float*)d_in[3];
    const float* mean  = (const float*)d_in[4];
    const float* var   = (const float*)d_in[5];
    float* out  = (float*)d_out;
    float* wT   = (float*)d_ws;                   // 32768 floats (128 KB)
    float* pscr = (float*)d_ws + CDIM * KDIM;     // 256*784 floats (~0.78 MB)

    prep_kernel<<<128, 256, 0, stream>>>(w16, gamma, var, wT);
    conv_kernel<<<BATCH, 512, 0, stream>>>(fm, wT, gamma, beta, mean, var, pscr);
    bp_kernel<<<BATCH, 512, 0, stream>>>(fm, pscr, out);
}

// Round 11
// 213.012 us; speedup vs baseline: 1.2610x; 1.2610x over previous
//
#include <hip/hip_runtime.h>

// Problem constants (fixed by the reference)
#define BATCH 256
#define CDIM  2048
#define HW    49
#define KDIM  16

#define OSTRIP 8                 // c-strips per image (conv) == c-chunks (bp)
#define SC     256               // c per strip
#define STRIP_B (SC * HW * 4)    // 50176 bytes per strip (== 49 * 1024)

// async global->LDS DMA, 16 B per lane: LDS dst = wave-uniform base + lane*16
// (linear); global src per-lane. Both 16B-aligned here.
#define GLDS(g, l) __builtin_amdgcn_global_load_lds(                        \
        (const __attribute__((address_space(1))) unsigned int*)(g),          \
        (__attribute__((address_space(3))) unsigned int*)(l), 16, 0, 0)

// Workspace (floats): wT[2048*16] at 0; pscr[2048*784] at 32768 (6.55 MB).
//   conv writes partials  pscr[(b*8+o)*784 + k*49 + hw]   (plain stores, NO atomics)
//   mid  rewrites in place pscr[b*6272 + hw*16 + k] = BN(sum_o partial)

// ---------------------------------------------------------------------------
// prep: wT[c][k] = w16[k][c] * gamma[k]*rsqrt(var+eps)/49  (BN scale + pool folded)
// ---------------------------------------------------------------------------
__global__ __launch_bounds__(256) void prep_kernel(
    const float* __restrict__ w16,
    const float* __restrict__ gamma, const float* __restrict__ var,
    float* __restrict__ wT)
{
    const int idx = blockIdx.x * 256 + threadIdx.x;   // grid 128 -> 32768 threads
    const int c = idx >> 4, k = idx & 15;
    const float inv = gamma[k] * rsqrtf(var[k] + 1e-5f) * (1.0f / 49.0f);
    wT[idx] = w16[k * CDIM + c] * inv;
}

// ---------------------------------------------------------------------------
// conv: partial[o][k][hw] = sum_{c in strip} wT[c][k]*fm[c][hw]
// grid = BATCH*8, block = 256 (4 waves, 64 c per wave).
// fm strip (49 KB) streamed to LDS via global_load_lds DMA; reduction scratch
// ALIASES fbuf (barrier-separated; alias+barriers correctness-proven in r8).
// 50 KB LDS -> 3 blocks/CU: read-rate scales with resident blocks (r6/r8 data).
// w read at wave-uniform addresses through __restrict__ global -> s_load.
// Plain partial stores (atomics measured +37us in r8 -> removed).
// ---------------------------------------------------------------------------
__global__ __launch_bounds__(256) void conv_kernel(
    const float* __restrict__ fm, const float* __restrict__ wT,
    float* __restrict__ pscr)
{
    __shared__ __align__(16) float fbuf[SC * HW + 4];   // 50192 B; red aliases head

    const int tid  = threadIdx.x;
    const int b    = blockIdx.x >> 3;
    const int o    = blockIdx.x & 7;
    const int wavu = __builtin_amdgcn_readfirstlane(tid >> 6);  // wave-uniform
    const int lane = tid & 63;
    const int hwi  = lane < HW ? lane : HW - 1;  // clamp: lanes>=49 discarded

    // ---- DMA the strip into LDS: 49 x 1024B wave-loads, split 13/12/12/12 ----
    {
        const char* gbase = (const char*)fm
            + (size_t)b * (CDIM * HW * 4) + (size_t)o * STRIP_B;
        char* lbase = (char*)fbuf;
        const int nld = (wavu == 0) ? 13 : 12;
        for (int i = 0; i < nld; ++i) {
            const int j = wavu + 4 * i;                 // 0..48, wave-uniform
            GLDS(gbase + j * 1024 + lane * 16, lbase + j * 1024);
        }
    }
    __syncthreads();   // vmcnt(0) drained before barrier -> strip visible

    float acc[KDIM];
    #pragma unroll
    for (int k = 0; k < KDIM; ++k) acc[k] = 0.f;

    const int cl0 = wavu * 64;                          // wave's local c-base
    const float4* __restrict__ wq = (const float4*)(wT + (size_t)((o * SC + cl0) << 4));

    #pragma unroll 8
    for (int cc = 0; cc < 64; ++cc) {
        const float fv = fbuf[(cl0 + cc) * HW + hwi];   // ds_read_b32, <=2-way
        const float4 w0 = wq[cc * 4 + 0];               // uniform -> s_load
        const float4 w1 = wq[cc * 4 + 1];
        const float4 w2 = wq[cc * 4 + 2];
        const float4 w3 = wq[cc * 4 + 3];
        acc[0]  += w0.x * fv; acc[1]  += w0.y * fv; acc[2]  += w0.z * fv; acc[3]  += w0.w * fv;
        acc[4]  += w1.x * fv; acc[5]  += w1.y * fv; acc[6]  += w1.z * fv; acc[7]  += w1.w * fv;
        acc[8]  += w2.x * fv; acc[9]  += w2.y * fv; acc[10] += w2.z * fv; acc[11] += w2.w * fv;
        acc[12] += w3.x * fv; acc[13] += w3.y * fv; acc[14] += w3.z * fv; acc[15] += w3.w * fv;
    }

    __syncthreads();   // all fbuf reads done -> safe to alias as reduction scratch
    float* red = fbuf; // needs 4*16*52 = 3328 floats << 12548
    if (lane < HW) {
        #pragma unroll
        for (int k = 0; k < KDIM; ++k)
            red[wavu * (KDIM * 52) + k * 52 + lane] = acc[k];
    }
    __syncthreads();

    // cross-wave reduce + plain store of strip partial [k][hw]
    for (int p = tid; p < HW * KDIM; p += 256) {
        const int k = p / HW, hw = p - k * HW;
        const int a = k * 52 + hw;
        const float s = red[a] + red[a + 832] + red[a + 1664] + red[a + 2496];
        pscr[(size_t)blockIdx.x * 784 + p] = s;
    }
}

// ---------------------------------------------------------------------------
// mid: P_bn[b][hw][k] = sum_o partial[o][k][hw] + shift[k]/49  (in-place, pscr)
// grid = BATCH, block = 256. All reads precede the barrier, writes after.
// (r6-verified)
// ---------------------------------------------------------------------------
__global__ __launch_bounds__(256) void mid_kernel(
    float* __restrict__ pscr,
    const float* __restrict__ gamma, const float* __restrict__ beta,
    const float* __restrict__ mean,  const float* __restrict__ var)
{
    const int tid  = threadIdx.x;
    const size_t base = (size_t)blockIdx.x * (OSTRIP * 784);
    float s0 = 0.f, s1 = 0.f, s2 = 0.f, s3 = 0.f;

#define MIDR(SV, R) { const int j = tid + 256 * (R); if (j < 784) {            \
        const int k = j & 15, hw = j >> 4;                                     \
        const size_t src = base + k * HW + hw;                                 \
        float t = 0.f;                                                         \
        _Pragma("unroll")                                                      \
        for (int oo = 0; oo < OSTRIP; ++oo) t += pscr[src + oo * 784];         \
        const float inv = gamma[k] * rsqrtf(var[k] + 1e-5f);                   \
        SV = t + (beta[k] - mean[k] * inv) * (1.0f / 49.0f); } }
    MIDR(s0, 0) MIDR(s1, 1) MIDR(s2, 2) MIDR(s3, 3)
#undef MIDR
    __syncthreads();
    if (tid < 784)        pscr[base + tid]       = s0;
    if (tid + 256 < 784)  pscr[base + tid + 256] = s1;
    if (tid + 512 < 784)  pscr[base + tid + 512] = s2;
    if (tid + 768 < 784)  pscr[base + tid + 768] = s3;
}

// ---------------------------------------------------------------------------
// bp: out[b][k][c] = sum_hw P_bn[hw][k] * fm[c][hw]
// grid = BATCH*8 (256 c per block), block = 256, 1 c per thread.
// fm chunk (49 KB) staged via global_load_lds DMA; 50 KB LDS -> 3 blocks/CU.
// P_bn block-uniform, never written here -> s_load (SGPR FMA operand).
// (r8-verified structure)
// ---------------------------------------------------------------------------
__global__ __launch_bounds__(256) void bp_kernel(
    const float* __restrict__ fm, const float* __restrict__ pscr,
    float* __restrict__ out)
{
    __shared__ __align__(16) float fs[SC * HW];      // 50176 B == 49*1024

    const int tid  = threadIdx.x;
    const int b    = blockIdx.x >> 3;
    const int oc   = (blockIdx.x & 7) * SC;
    const int wavu = __builtin_amdgcn_readfirstlane(tid >> 6);
    const int lane = tid & 63;

    // ---- DMA the c-chunk into LDS: identical strip shape to conv ----
    {
        const char* gbase = (const char*)fm + ((size_t)b * CDIM + oc) * (HW * 4);
        char* lbase = (char*)fs;
        const int nld = (wavu == 0) ? 13 : 12;
        for (int i = 0; i < nld; ++i) {
            const int j = wavu + 4 * i;
            GLDS(gbase + j * 1024 + lane * 16, lbase + j * 1024);
        }
    }
    __syncthreads();

    const float4* __restrict__ P4 = (const float4*)(pscr + (size_t)b * (OSTRIP * 784));

    float acc[KDIM];
    #pragma unroll
    for (int k = 0; k < KDIM; ++k) acc[k] = 0.f;

    const float* row = fs + tid * HW;                // stride 49 (odd) -> 2-way, free
    #pragma unroll
    for (int hw = 0; hw < HW; ++hw) {
        const float fv = row[hw];
        const float4 p0 = P4[hw * 4 + 0];            // uniform -> s_load
        const float4 p1 = P4[hw * 4 + 1];
        const float4 p2 = P4[hw * 4 + 2];
        const float4 p3 = P4[hw * 4 + 3];
        acc[0]  += p0.x * fv; acc[1]  += p0.y * fv; acc[2]  += p0.z * fv; acc[3]  += p0.w * fv;
        acc[4]  += p1.x * fv; acc[5]  += p1.y * fv; acc[6]  += p1.z * fv; acc[7]  += p1.w * fv;
        acc[8]  += p2.x * fv; acc[9]  += p2.y * fv; acc[10] += p2.z * fv; acc[11] += p2.w * fv;
        acc[12] += p3.x * fv; acc[13] += p3.y * fv; acc[14] += p3.z * fv; acc[15] += p3.w * fv;
    }

    float* ob = out + (size_t)b * (KDIM * CDIM) + oc + tid;
    #pragma unroll
    for (int k = 0; k < KDIM; ++k) ob[k * CDIM] = acc[k];
}

extern "C" void kernel_launch(void* const* d_in, const int* in_sizes, int n_in,
                              void* d_out, int out_size, void* d_ws, size_t ws_size,
                              hipStream_t stream) {
    const float* fm    = (const float*)d_in[0];
    const float* w16   = (const float*)d_in[1];
    const float* gamma = (const float*)d_in[2];
    const float* beta  = (const float*)d_in[3];
    const float* mean  = (const float*)d_in[4];
    const float* var   = (const float*)d_in[5];
    float* out  = (float*)d_out;
    float* wT   = (float*)d_ws;                   // 32768 floats (128 KB)
    float* pscr = (float*)d_ws + CDIM * KDIM;     // 2048*784 floats (6.4 MB)

    prep_kernel<<<128, 256, 0, stream>>>(w16, gamma, var, wT);
    conv_kernel<<<BATCH * OSTRIP, 256, 0, stream>>>(fm, wT, pscr);
    mid_kernel<<<BATCH, 256, 0, stream>>>(pscr, gamma, beta, mean, var);
    bp_kernel<<<BATCH * OSTRIP, 256, 0, stream>>>(fm, pscr, out);
}

// Round 13
// 208.203 us; speedup vs baseline: 1.2901x; 1.0231x over previous
//
#include <hip/hip_runtime.h>

// Problem constants (fixed by the reference)
#define BATCH 256
#define CDIM  2048
#define HW    49
#define KDIM  16

#define OSTRIP 8                 // c-strips per image (conv)
#define SC     256               // c per strip
#define STRIP_B (SC * HW * 4)    // 50176 bytes per strip (== 49 * 1024)

// 4-float vector with 4-byte alignment (fm rows start at c*196 B)
typedef float f4u __attribute__((ext_vector_type(4), aligned(4)));

// async global->LDS DMA, 16 B per lane: LDS dst = wave-uniform base + lane*16
#define GLDS(g, l) __builtin_amdgcn_global_load_lds(                        \
        (const __attribute__((address_space(1))) unsigned int*)(g),          \
        (__attribute__((address_space(3))) unsigned int*)(l), 16, 0, 0)

// Workspace (floats): wT[2048*16] at 0; pscr[2048*784] at 32768 (6.55 MB).
//   conv writes partials  pscr[(b*8+o)*784 + k*49 + hw]   (plain stores)
//   mid  rewrites in place pscr[b*6272 + hw*16 + k] = BN(sum_o partial)

// ---------------------------------------------------------------------------
// prep: wT[c][k] = w16[k][c] * gamma[k]*rsqrt(var+eps)/49  (r11-verified)
// ---------------------------------------------------------------------------
__global__ __launch_bounds__(256) void prep_kernel(
    const float* __restrict__ w16,
    const float* __restrict__ gamma, const float* __restrict__ var,
    float* __restrict__ wT)
{
    const int idx = blockIdx.x * 256 + threadIdx.x;
    const int c = idx >> 4, k = idx & 15;
    const float inv = gamma[k] * rsqrtf(var[k] + 1e-5f) * (1.0f / 49.0f);
    wT[idx] = w16[k * CDIM + c] * inv;
}

// ---------------------------------------------------------------------------
// conv: partial[o][k][hw] = sum_{c in strip} wT[c][k]*fm[c][hw]
// (r11-verified, byte-identical: GLDS strip, 3 blocks/CU, s_load w, plain store)
// ---------------------------------------------------------------------------
__global__ __launch_bounds__(256) void conv_kernel(
    const float* __restrict__ fm, const float* __restrict__ wT,
    float* __restrict__ pscr)
{
    __shared__ __align__(16) float fbuf[SC * HW + 4];   // 50192 B; red aliases head

    const int tid  = threadIdx.x;
    const int b    = blockIdx.x >> 3;
    const int o    = blockIdx.x & 7;
    const int wavu = __builtin_amdgcn_readfirstlane(tid >> 6);
    const int lane = tid & 63;
    const int hwi  = lane < HW ? lane : HW - 1;

    {
        const char* gbase = (const char*)fm
            + (size_t)b * (CDIM * HW * 4) + (size_t)o * STRIP_B;
        char* lbase = (char*)fbuf;
        const int nld = (wavu == 0) ? 13 : 12;
        for (int i = 0; i < nld; ++i) {
            const int j = wavu + 4 * i;                 // 0..48, wave-uniform
            GLDS(gbase + j * 1024 + lane * 16, lbase + j * 1024);
        }
    }
    __syncthreads();

    float acc[KDIM];
    #pragma unroll
    for (int k = 0; k < KDIM; ++k) acc[k] = 0.f;

    const int cl0 = wavu * 64;
    const float4* __restrict__ wq = (const float4*)(wT + (size_t)((o * SC + cl0) << 4));

    #pragma unroll 8
    for (int cc = 0; cc < 64; ++cc) {
        const float fv = fbuf[(cl0 + cc) * HW + hwi];   // ds_read_b32, <=2-way
        const float4 w0 = wq[cc * 4 + 0];               // uniform -> s_load
        const float4 w1 = wq[cc * 4 + 1];
        const float4 w2 = wq[cc * 4 + 2];
        const float4 w3 = wq[cc * 4 + 3];
        acc[0]  += w0.x * fv; acc[1]  += w0.y * fv; acc[2]  += w0.z * fv; acc[3]  += w0.w * fv;
        acc[4]  += w1.x * fv; acc[5]  += w1.y * fv; acc[6]  += w1.z * fv; acc[7]  += w1.w * fv;
        acc[8]  += w2.x * fv; acc[9]  += w2.y * fv; acc[10] += w2.z * fv; acc[11] += w2.w * fv;
        acc[12] += w3.x * fv; acc[13] += w3.y * fv; acc[14] += w3.z * fv; acc[15] += w3.w * fv;
    }

    __syncthreads();
    float* red = fbuf;
    if (lane < HW) {
        #pragma unroll
        for (int k = 0; k < KDIM; ++k)
            red[wavu * (KDIM * 52) + k * 52 + lane] = acc[k];
    }
    __syncthreads();

    for (int p = tid; p < HW * KDIM; p += 256) {
        const int k = p / HW, hw = p - k * HW;
        const int a = k * 52 + hw;
        const float s = red[a] + red[a + 832] + red[a + 1664] + red[a + 2496];
        pscr[(size_t)blockIdx.x * 784 + p] = s;
    }
}

// ---------------------------------------------------------------------------
// mid: P_bn[b][hw][k] = sum_o partial[o][k][hw] + shift[k]/49  (r11-verified)
// ---------------------------------------------------------------------------
__global__ __launch_bounds__(256) void mid_kernel(
    float* __restrict__ pscr,
    const float* __restrict__ gamma, const float* __restrict__ beta,
    const float* __restrict__ mean,  const float* __restrict__ var)
{
    const int tid  = threadIdx.x;
    const size_t base = (size_t)blockIdx.x * (OSTRIP * 784);
    float s0 = 0.f, s1 = 0.f, s2 = 0.f, s3 = 0.f;

#define MIDR(SV, R) { const int j = tid + 256 * (R); if (j < 784) {            \
        const int k = j & 15, hw = j >> 4;                                     \
        const size_t src = base + k * HW + hw;                                 \
        float t = 0.f;                                                         \
        _Pragma("unroll")                                                      \
        for (int oo = 0; oo < OSTRIP; ++oo) t += pscr[src + oo * 784];         \
        const float inv = gamma[k] * rsqrtf(var[k] + 1e-5f);                   \
        SV = t + (beta[k] - mean[k] * inv) * (1.0f / 49.0f); } }
    MIDR(s0, 0) MIDR(s1, 1) MIDR(s2, 2) MIDR(s3, 3)
#undef MIDR
    __syncthreads();
    if (tid < 784)        pscr[base + tid]       = s0;
    if (tid + 256 < 784)  pscr[base + tid + 256] = s1;
    if (tid + 512 < 784)  pscr[base + tid + 512] = s2;
    if (tid + 768 < 784)  pscr[base + tid + 768] = s3;
}

// ---------------------------------------------------------------------------
// bp: out[b][k][c] = sum_hw P_bn[hw][k] * fm[c][hw]
// VGPR-direct, no LDS. Thread owns c; loads its whole 196-B row up front
// (12 x f4u + 1 dword = 13 loads in flight per thread, ~13 KB/wave).
// No LDS -> occupancy VGPR-bound: __launch_bounds__(256,6) -> ~24 waves/CU,
// ~300 KB reads in flight per CU (max-MLP probe of the read wall).
// P_bn block-uniform, never written here -> s_load on lgkm pipe (decoupled
// from the f-loads' vmcnt).
// ---------------------------------------------------------------------------
__global__ __launch_bounds__(256, 6) void bp_kernel(
    const float* __restrict__ fm, const float* __restrict__ pscr,
    float* __restrict__ out)
{
    const int tid = threadIdx.x;
    const int b   = blockIdx.x >> 3;
    const int c   = ((blockIdx.x & 7) << 8) + tid;

    const float* __restrict__ row = fm + ((size_t)b * CDIM + c) * HW;

    // load the full row into registers: 12 x 16B + 1 x 4B, all issued back-to-back
    f4u fr[12];
    #pragma unroll
    for (int i = 0; i < 12; ++i) fr[i] = *(const f4u*)(row + i * 4);
    const float ft = row[48];

    const float4* __restrict__ P4 = (const float4*)(pscr + (size_t)b * (OSTRIP * 784));

    float acc[KDIM];
    #pragma unroll
    for (int k = 0; k < KDIM; ++k) acc[k] = 0.f;

    #pragma unroll
    for (int hw = 0; hw < HW; ++hw) {
        const float fv = (hw < 48) ? fr[hw >> 2][hw & 3] : ft;   // static after unroll
        const float4 p0 = P4[hw * 4 + 0];     // uniform -> s_load (lgkm pipe)
        const float4 p1 = P4[hw * 4 + 1];
        const float4 p2 = P4[hw * 4 + 2];
        const float4 p3 = P4[hw * 4 + 3];
        acc[0]  += p0.x * fv; acc[1]  += p0.y * fv; acc[2]  += p0.z * fv; acc[3]  += p0.w * fv;
        acc[4]  += p1.x * fv; acc[5]  += p1.y * fv; acc[6]  += p1.z * fv; acc[7]  += p1.w * fv;
        acc[8]  += p2.x * fv; acc[9]  += p2.y * fv; acc[10] += p2.z * fv; acc[11] += p2.w * fv;
        acc[12] += p3.x * fv; acc[13] += p3.y * fv; acc[14] += p3.z * fv; acc[15] += p3.w * fv;
    }

    float* ob = out + (size_t)b * (KDIM * CDIM) + c;
    #pragma unroll
    for (int k = 0; k < KDIM; ++k) ob[k * CDIM] = acc[k];
}

extern "C" void kernel_launch(void* const* d_in, const int* in_sizes, int n_in,
                              void* d_out, int out_size, void* d_ws, size_t ws_size,
                              hipStream_t stream) {
    const float* fm    = (const float*)d_in[0];
    const float* w16   = (const float*)d_in[1];
    const float* gamma = (const float*)d_in[2];
    const float* beta  = (const float*)d_in[3];
    const float* mean  = (const float*)d_in[4];
    const float* var   = (const float*)d_in[5];
    float* out  = (float*)d_out;
    float* wT   = (float*)d_ws;                   // 32768 floats (128 KB)
    float* pscr = (float*)d_ws + CDIM * KDIM;     // 2048*784 floats (6.4 MB)

    prep_kernel<<<128, 256, 0, stream>>>(w16, gamma, var, wT);
    conv_kernel<<<BATCH * OSTRIP, 256, 0, stream>>>(fm, wT, pscr);
    mid_kernel<<<BATCH, 256, 0, stream>>>(pscr, gamma, beta, mean, var);
    bp_kernel<<<BATCH * OSTRIP, 256, 0, stream>>>(fm, pscr, out);
}